// Round 11
// baseline (1535.336 us; speedup 1.0000x reference)
//
#include <hip/hip_runtime.h>
#include <math.h>

#define NBOX 1000
#define NIMG 2
#define CCH 256
#define FCIN 12544   // 256*7*7
#define FCD 1024
#define TOPK 100
#define SCALE_CLAMP_F ((float)4.135166556742356)  // f32(np.log(1000/16))
#define KC 384       // OpenBLAS SGEMM_DEFAULT_Q (k-panel size) -- FROZEN numerics invariant
#define R1 16        // rows per block (does not affect numerics)

// ---------------- Prep: per-box level + gather indices (strict f32, numpy op order) ----------------
__global__ void prep_kernel(const float* __restrict__ props, int* __restrict__ prep) {
    int b = blockIdx.x * blockDim.x + threadIdx.x;
    if (b >= NIMG * NBOX) return;
    int n = b / NBOX;
    const float* pr = props + (size_t)b * 4;
    float x1 = pr[0], y1 = pr[1], x2 = pr[2], y2 = pr[3];

    float w = __fsub_rn(x2, x1), h = __fsub_rn(y2, y1);
    float s = sqrtf(fmaxf(__fmul_rn(w, h), 1e-6f));
    float l2 = (float)log2((double)__fadd_rn(__fdiv_rn(s, 224.0f), 1e-8f));
    float lv = floorf(__fadd_rn(4.0f, l2));
    lv = fminf(fmaxf(lv, 2.0f), 5.0f);
    int lvl = (int)lv - 2;

    int H, W; float scale;
    if (lvl == 0)      { H = 200; W = 304; scale = 0.25f; }
    else if (lvl == 1) { H = 100; W = 152; scale = 0.125f; }
    else if (lvl == 2) { H = 50;  W = 76;  scale = 0.0625f; }
    else               { H = 25;  W = 38;  scale = 0.03125f; }

    float xs1 = __fmul_rn(x1, scale), ys1 = __fmul_rn(y1, scale);
    float xs2 = __fmul_rn(x2, scale), ys2 = __fmul_rn(y2, scale);
    float bw = __fdiv_rn(fmaxf(__fsub_rn(xs2, xs1), 1.0f), 7.0f);
    float bh = __fdiv_rn(fmaxf(__fsub_rn(ys2, ys1), 1.0f), 7.0f);

    int* pb = prep + b * 20;
    pb[0] = lvl;
    pb[1] = n * CCH * H * W;
    pb[2] = H * W;
#pragma unroll
    for (int i = 0; i < 7; i++) {
        float cs = (float)i + 0.5f;
        float gx = __fadd_rn(xs1, __fmul_rn(cs, bw));
        float gy = __fadd_rn(ys1, __fmul_rn(cs, bh));
        int vx = (int)gx;
        int vy = (int)gy;
        vx = vx < 0 ? 0 : (vx > W - 1 ? W - 1 : vx);
        vy = vy < 0 ? 0 : (vy > H - 1 ? H - 1 : vy);
        pb[4 + i] = vx;
        pb[12 + i] = vy * W;
    }
}

// ---------------- Panel body: KT x (16 rows x 1 col), double-buffered W prefetch ----------------
// Numerics: per output element, ascending-k fma chain over the panel -- IDENTICAL order to rounds 8-10.
#define FMA16(BUF, KB)                                                \
    _Pragma("unroll")                                                 \
    for (int u = 0; u < 8; u++) {                                     \
        const float4* xv = (const float4*)&xs[(KB) + u][0];           \
        float4 a0 = xv[0], a1 = xv[1], a2 = xv[2], a3 = xv[3];        \
        float w = BUF[u];                                             \
        acc[0]  = fmaf(a0.x, w, acc[0]);                              \
        acc[1]  = fmaf(a0.y, w, acc[1]);                              \
        acc[2]  = fmaf(a0.z, w, acc[2]);                              \
        acc[3]  = fmaf(a0.w, w, acc[3]);                              \
        acc[4]  = fmaf(a1.x, w, acc[4]);                              \
        acc[5]  = fmaf(a1.y, w, acc[5]);                              \
        acc[6]  = fmaf(a1.z, w, acc[6]);                              \
        acc[7]  = fmaf(a1.w, w, acc[7]);                              \
        acc[8]  = fmaf(a2.x, w, acc[8]);                              \
        acc[9]  = fmaf(a2.y, w, acc[9]);                              \
        acc[10] = fmaf(a2.z, w, acc[10]);                             \
        acc[11] = fmaf(a2.w, w, acc[11]);                             \
        acc[12] = fmaf(a3.x, w, acc[12]);                             \
        acc[13] = fmaf(a3.y, w, acc[13]);                             \
        acc[14] = fmaf(a3.z, w, acc[14]);                             \
        acc[15] = fmaf(a3.w, w, acc[15]);                             \
    }

template <int KT>
__device__ __forceinline__ void fc_panel(const float* __restrict__ wp,
                                         const float (*xs)[R1],
                                         float acc[R1]) {
    float wa[8], wb[8];
#pragma unroll
    for (int u = 0; u < 8; u++) wa[u] = wp[(size_t)u * FCD];
    for (int kk = 0; kk < KT; kk += 16) {
#pragma unroll
        for (int u = 0; u < 8; u++)
            wb[u] = wp[(size_t)(kk + 8 + u) * FCD];
        FMA16(wa, kk)                      // k = kk .. kk+7 (ascending)
        if (kk + 16 < KT) {
#pragma unroll
            for (int u = 0; u < 8; u++)
                wa[u] = wp[(size_t)(kk + 16 + u) * FCD];
        }
        FMA16(wb, kk + 8)                  // k = kk+8 .. kk+15 (ascending)
    }
}

// ---------------- FC1: fused gather + sgemm-order f32 (KC=384 panels) + bias + ReLU ----------------
// 16 rows/block, 1 col/thread: halves W L3 traffic vs round 10 (16 FMA per 4B of W).
__global__ __launch_bounds__(256) void fc1_seq(
    const float* __restrict__ p2, const float* __restrict__ p3,
    const float* __restrict__ p4, const float* __restrict__ p5,
    const int* __restrict__ prep, const float* __restrict__ W1,
    const float* __restrict__ b1, float* __restrict__ X1) {
    __shared__ float xs[KC][R1];
    __shared__ int s_ix[R1][7], s_iyW[R1][7], s_HW[R1];
    __shared__ const float* s_fp[R1];

    int tid = threadIdx.x;
    int col = blockIdx.x * 256 + tid;
    int row0 = blockIdx.y * R1;

    if (tid < R1) {
        const int* pb = prep + (row0 + tid) * 20;
        int lvl = pb[0];
        s_fp[tid] = (lvl == 0 ? p2 : lvl == 1 ? p3 : lvl == 2 ? p4 : p5) + pb[1];
        s_HW[tid] = pb[2];
#pragma unroll
        for (int j = 0; j < 7; j++) { s_ix[tid][j] = pb[4 + j]; s_iyW[tid][j] = pb[12 + j]; }
    }

    float tot[R1];
#pragma unroll
    for (int r = 0; r < R1; r++) tot[r] = 0.0f;

    for (int k0 = 0; k0 < FCIN; k0 += KC) {
        int kt = FCIN - k0; if (kt > KC) kt = KC;   // 384 or 256
        __syncthreads();
        for (int e = tid; e < kt * R1; e += 256) {
            int kk = e >> 4;
            int r = e & 15;
            int k = k0 + kk;
            int c = k / 49;
            int p = k - c * 49;
            int gy = p / 7;
            int gx = p - gy * 7;
            xs[kk][r] = s_fp[r][c * s_HW[r] + s_iyW[r][gy] + s_ix[r][gx]];
        }
        __syncthreads();

        float acc[R1];
#pragma unroll
        for (int r = 0; r < R1; r++) acc[r] = 0.0f;

        const float* wp = W1 + (size_t)k0 * FCD + col;
        if (kt == KC) fc_panel<KC>(wp, xs, acc);
        else          fc_panel<256>(wp, xs, acc);

        // panel left-fold (C += panel) -- frozen order
#pragma unroll
        for (int r = 0; r < R1; r++) tot[r] = __fadd_rn(tot[r], acc[r]);
    }
    float bv = b1[col];
#pragma unroll
    for (int r = 0; r < R1; r++) {
        float v = __fadd_rn(tot[r], bv);
        X1[(size_t)(row0 + r) * FCD + col] = fmaxf(v, 0.0f);
    }
}

// ---------------- FC2: sgemm-order f32 (KC=384 panels) + bias + ReLU ----------------
__global__ __launch_bounds__(256) void fc2_seq(
    const float* __restrict__ X1, const float* __restrict__ W2,
    const float* __restrict__ b2, float* __restrict__ X2) {
    __shared__ float xs[KC][R1];
    int tid = threadIdx.x;
    int col = blockIdx.x * 256 + tid;
    int row0 = blockIdx.y * R1;

    float tot[R1];
#pragma unroll
    for (int r = 0; r < R1; r++) tot[r] = 0.0f;

    for (int k0 = 0; k0 < FCD; k0 += KC) {
        int kt = FCD - k0; if (kt > KC) kt = KC;
        __syncthreads();
        for (int e = tid; e < kt * R1; e += 256) {
            int kk = e >> 4;
            int r = e & 15;
            xs[kk][r] = X1[(size_t)(row0 + r) * FCD + k0 + kk];
        }
        __syncthreads();

        float acc[R1];
#pragma unroll
        for (int r = 0; r < R1; r++) acc[r] = 0.0f;

        const float* wp = W2 + (size_t)k0 * FCD + col;
        if (kt == KC) fc_panel<KC>(wp, xs, acc);
        else          fc_panel<256>(wp, xs, acc);

#pragma unroll
        for (int r = 0; r < R1; r++) tot[r] = __fadd_rn(tot[r], acc[r]);
    }
    float bv = b2[col];
#pragma unroll
    for (int r = 0; r < R1; r++) {
        float v = __fadd_rn(tot[r], bv);
        X2[(size_t)(row0 + r) * FCD + col] = fmaxf(v, 0.0f);
    }
}

// ---------------- Heads: 6 sgemm-order dots (KC panels), softmax, decode, clip ----------------
__global__ __launch_bounds__(256) void heads_seq(
    const float* __restrict__ X2,
    const float* __restrict__ Wc, const float* __restrict__ bc,
    const float* __restrict__ Wb, const float* __restrict__ bb_,
    const float* __restrict__ props, const int* __restrict__ img_sz,
    float* __restrict__ SC, float* __restrict__ BX) {
    int b = blockIdx.x;
    int tid = threadIdx.x;
    __shared__ float xsh[FCD];
    __shared__ float lg[6];
    for (int k = tid; k < FCD; k += 256) xsh[k] = X2[(size_t)b * FCD + k];
    __syncthreads();

    if (tid < 6) {
        const float* wp; int st; float bias;
        if (tid < 2) { wp = Wc + tid; st = 2; bias = bc[tid]; }
        else         { wp = Wb + (tid - 2); st = 4; bias = bb_[tid - 2]; }
        float tot = 0.0f;
        for (int k0 = 0; k0 < FCD; k0 += KC) {
            int kt = FCD - k0; if (kt > KC) kt = KC;
            float acc = 0.0f;
            for (int k = k0; k < k0 + kt; k++) acc = fmaf(xsh[k], wp[(size_t)k * st], acc);
            tot = __fadd_rn(tot, acc);
        }
        lg[tid] = __fadd_rn(tot, bias);
    }
    __syncthreads();

    if (tid == 0) {
        float c0 = lg[0], c1 = lg[1];
        float mx = fmaxf(c0, c1);
        float e0 = (float)exp((double)__fsub_rn(c0, mx));
        float e1 = (float)exp((double)__fsub_rn(c1, mx));
        SC[b] = __fdiv_rn(e1, __fadd_rn(e0, e1));

        int n = b / NBOX;
        const float* pr = props + (size_t)b * 4;
        float x1 = pr[0], y1 = pr[1], x2 = pr[2], y2 = pr[3];
        float w = __fsub_rn(x2, x1), h = __fsub_rn(y2, y1);
        float cx = __fadd_rn(x1, __fmul_rn(0.5f, w));
        float cy = __fadd_rn(y1, __fmul_rn(0.5f, h));
        float dx = lg[2], dy = lg[3];
        float dw = fminf(lg[4], SCALE_CLAMP_F);
        float dh = fminf(lg[5], SCALE_CLAMP_F);
        float pcx = __fadd_rn(__fmul_rn(dx, w), cx);
        float pcy = __fadd_rn(__fmul_rn(dy, h), cy);
        float pw = __fmul_rn((float)exp((double)dw), w);
        float ph = __fmul_rn((float)exp((double)dh), h);
        float bx1 = __fsub_rn(pcx, __fmul_rn(0.5f, pw));
        float by1 = __fsub_rn(pcy, __fmul_rn(0.5f, ph));
        float bx2 = __fadd_rn(pcx, __fmul_rn(0.5f, pw));
        float by2 = __fadd_rn(pcy, __fmul_rn(0.5f, ph));
        float Hf = (float)img_sz[n * 2 + 0], Wf = (float)img_sz[n * 2 + 1];
        bx1 = fminf(fmaxf(bx1, 0.0f), Wf);
        by1 = fminf(fmaxf(by1, 0.0f), Hf);
        bx2 = fminf(fmaxf(bx2, 0.0f), Wf);
        by2 = fminf(fmaxf(by2, 0.0f), Hf);
        BX[(size_t)b * 4 + 0] = bx1;
        BX[(size_t)b * 4 + 1] = by1;
        BX[(size_t)b * 4 + 2] = bx2;
        BX[(size_t)b * 4 + 3] = by2;
    }
}

// ---------------- Sort + NMS + topk (strict f32, numpy op order) ----------------
__global__ __launch_bounds__(1024) void nms_kernel(const float* __restrict__ SC,
                                                   const float* __restrict__ BX,
                                                   float* __restrict__ out) {
    int n = blockIdx.x;
    __shared__ float sraw[NBOX];
    __shared__ float ssort[NBOX];
    __shared__ float bsort[NBOX][4];
    __shared__ int ord[NBOX];
    __shared__ unsigned char keep[NBOX];
    int tid = threadIdx.x;

    for (int j = tid; j < NBOX; j += 1024) sraw[j] = SC[n * NBOX + j];
    __syncthreads();

    if (tid < NBOX) {
        float sj = sraw[tid];
        int r = 0;
        for (int k = 0; k < NBOX; k++) {
            float sk = sraw[k];
            r += (sk > sj) || (sk == sj && k < tid);
        }
        ord[r] = tid;
        ssort[r] = sj;
#pragma unroll
        for (int k = 0; k < 4; k++) bsort[r][k] = BX[((size_t)n * NBOX + tid) * 4 + k];
        keep[r] = (sj > 0.05f) ? 1 : 0;
    }
    __syncthreads();

    for (int i = 0; i < NBOX - 1; i++) {
        if (keep[i] && tid > i && tid < NBOX && keep[tid]) {
            float ax1 = bsort[i][0], ay1 = bsort[i][1], ax2 = bsort[i][2], ay2 = bsort[i][3];
            float bx1 = bsort[tid][0], by1 = bsort[tid][1], bx2 = bsort[tid][2], by2 = bsort[tid][3];
            float areaA = __fmul_rn(__fsub_rn(ax2, ax1), __fsub_rn(ay2, ay1));
            float areaB = __fmul_rn(__fsub_rn(bx2, bx1), __fsub_rn(by2, by1));
            float ix1 = fmaxf(ax1, bx1), iy1 = fmaxf(ay1, by1);
            float ix2 = fminf(ax2, bx2), iy2 = fminf(ay2, by2);
            float iw = fmaxf(__fsub_rn(ix2, ix1), 0.0f);
            float ih = fmaxf(__fsub_rn(iy2, iy1), 0.0f);
            float inter = __fmul_rn(iw, ih);
            float denom = fmaxf(__fsub_rn(__fadd_rn(areaA, areaB), inter), 1e-9f);
            if (__fdiv_rn(inter, denom) > 0.5f) keep[tid] = 0;
        }
        __syncthreads();
    }

    if (tid == 0) {
        int c = 0;
        for (int r = 0; r < NBOX; r++) {
            int k = keep[r];
            c += k;
            keep[r] = (k && (c <= TOPK)) ? 1 : 0;
        }
    }
    __syncthreads();

    float* boxes_o = out;
    float* scores_o = out + (size_t)NIMG * NBOX * 4;
    float* keep_o = scores_o + (size_t)NIMG * NBOX;
    float* ord_o = keep_o + (size_t)NIMG * NBOX;
    for (int r = tid; r < NBOX; r += 1024) {
#pragma unroll
        for (int k = 0; k < 4; k++)
            boxes_o[((size_t)n * NBOX + r) * 4 + k] = bsort[r][k];
        scores_o[n * NBOX + r] = ssort[r];
        keep_o[n * NBOX + r] = (float)keep[r];
        ord_o[n * NBOX + r] = (float)ord[r];
    }
}

extern "C" void kernel_launch(void* const* d_in, const int* in_sizes, int n_in,
                              void* d_out, int out_size, void* d_ws, size_t ws_size,
                              hipStream_t stream) {
    const float* p2 = (const float*)d_in[0];
    const float* p3 = (const float*)d_in[1];
    const float* p4 = (const float*)d_in[2];
    const float* p5 = (const float*)d_in[3];
    const float* props = (const float*)d_in[4];
    const int* img = (const int*)d_in[5];
    const float* W1 = (const float*)d_in[6];
    const float* b1 = (const float*)d_in[7];
    const float* W2 = (const float*)d_in[8];
    const float* b2 = (const float*)d_in[9];
    const float* Wc = (const float*)d_in[10];
    const float* bc = (const float*)d_in[11];
    const float* Wb = (const float*)d_in[12];
    const float* bb = (const float*)d_in[13];

    float* X1 = (float*)d_ws;
    float* X2 = X1 + (size_t)2000 * FCD;
    float* SCf = X2 + (size_t)2000 * FCD;
    float* BXf = SCf + 2000;
    int* prep = (int*)(BXf + 8000);

    prep_kernel<<<(NIMG * NBOX + 255) / 256, 256, 0, stream>>>(props, prep);

    dim3 gfc(4, (NIMG * NBOX) / R1);                   // (4, 125): 256 cols x 16 rows per block
    fc1_seq<<<gfc, 256, 0, stream>>>(p2, p3, p4, p5, prep, W1, b1, X1);
    fc2_seq<<<gfc, 256, 0, stream>>>(X1, W2, b2, X2);

    heads_seq<<<NIMG * NBOX, 256, 0, stream>>>(X2, Wc, bc, Wb, bb, props, img, SCf, BXf);

    nms_kernel<<<NIMG, 1024, 0, stream>>>(SCf, BXf, (float*)d_out);
}

// Round 12
// 1325.954 us; speedup vs baseline: 1.1579x; 1.1579x over previous
//
#include <hip/hip_runtime.h>
#include <math.h>

#define NBOX 1000
#define NIMG 2
#define CCH 256
#define FCIN 12544   // 256*7*7
#define FCD 1024
#define TOPK 100
#define SCALE_CLAMP_F ((float)4.135166556742356)  // f32(np.log(1000/16))
#define KC 384       // OpenBLAS SGEMM_DEFAULT_Q -- FROZEN numerics invariant
#define NPANEL 33    // 12544 = 32*384 + 256
#define RB 16        // rows per panel-block
#define NGROUP 125   // 2000/16
#define R1 8         // rows per block, fallback/fc2 path

// ---------------- Prep: per-box level + gather indices (strict f32, numpy op order) ----------------
__global__ void prep_kernel(const float* __restrict__ props, int* __restrict__ prep) {
    int b = blockIdx.x * blockDim.x + threadIdx.x;
    if (b >= NIMG * NBOX) return;
    int n = b / NBOX;
    const float* pr = props + (size_t)b * 4;
    float x1 = pr[0], y1 = pr[1], x2 = pr[2], y2 = pr[3];

    float w = __fsub_rn(x2, x1), h = __fsub_rn(y2, y1);
    float s = sqrtf(fmaxf(__fmul_rn(w, h), 1e-6f));
    float l2 = (float)log2((double)__fadd_rn(__fdiv_rn(s, 224.0f), 1e-8f));
    float lv = floorf(__fadd_rn(4.0f, l2));
    lv = fminf(fmaxf(lv, 2.0f), 5.0f);
    int lvl = (int)lv - 2;

    int H, W; float scale;
    if (lvl == 0)      { H = 200; W = 304; scale = 0.25f; }
    else if (lvl == 1) { H = 100; W = 152; scale = 0.125f; }
    else if (lvl == 2) { H = 50;  W = 76;  scale = 0.0625f; }
    else               { H = 25;  W = 38;  scale = 0.03125f; }

    float xs1 = __fmul_rn(x1, scale), ys1 = __fmul_rn(y1, scale);
    float xs2 = __fmul_rn(x2, scale), ys2 = __fmul_rn(y2, scale);
    float bw = __fdiv_rn(fmaxf(__fsub_rn(xs2, xs1), 1.0f), 7.0f);
    float bh = __fdiv_rn(fmaxf(__fsub_rn(ys2, ys1), 1.0f), 7.0f);

    int* pb = prep + b * 20;
    pb[0] = lvl;
    pb[1] = n * CCH * H * W;
    pb[2] = H * W;
#pragma unroll
    for (int i = 0; i < 7; i++) {
        float cs = (float)i + 0.5f;
        float gx = __fadd_rn(xs1, __fmul_rn(cs, bw));
        float gy = __fadd_rn(ys1, __fmul_rn(cs, bh));
        int vx = (int)gx;
        int vy = (int)gy;
        vx = vx < 0 ? 0 : (vx > W - 1 ? W - 1 : vx);
        vy = vy < 0 ? 0 : (vy > H - 1 ? H - 1 : vy);
        pb[4 + i] = vx;
        pb[12 + i] = vy * W;
    }
}

// ================= NEW: panel-parallel FC1 =================
// Each block: ONE panel p, 16 rows, all 1024 cols (128 thr x 8 cols).
// Computes the panel's raw ascending-k fma chain (exact) -> partials.
#define LOAD8(DST, Q)                                  \
    {                                                  \
        float4 t0 = *(const float4*)(Q);               \
        float4 t1 = *(const float4*)((Q) + 4);         \
        DST[0] = t0.x; DST[1] = t0.y; DST[2] = t0.z; DST[3] = t0.w; \
        DST[4] = t1.x; DST[5] = t1.y; DST[6] = t1.z; DST[7] = t1.w; \
    }

#define FMABLK(KB, WBUF)                                              \
    {                                                                 \
        const float4* xv = (const float4*)&xs[(KB)][0];               \
        float4 a0 = xv[0], a1 = xv[1], a2 = xv[2], a3 = xv[3];        \
        float xr[16] = {a0.x, a0.y, a0.z, a0.w, a1.x, a1.y, a1.z, a1.w, \
                        a2.x, a2.y, a2.z, a2.w, a3.x, a3.y, a3.z, a3.w}; \
        _Pragma("unroll")                                             \
        for (int r = 0; r < RB; r++) {                                \
            _Pragma("unroll")                                         \
            for (int j = 0; j < 8; j++)                               \
                acc[r][j] = fmaf(xr[r], WBUF[j], acc[r][j]);          \
        }                                                             \
    }

template <int KT>
__global__ __launch_bounds__(128, 2) void fc1_panel(
    const float* __restrict__ p2, const float* __restrict__ p3,
    const float* __restrict__ p4, const float* __restrict__ p5,
    const int* __restrict__ prep, const float* __restrict__ W1,
    float* __restrict__ part, int g0, int gs, int p_base) {
    __shared__ float xs[KT][RB];
    __shared__ int s_ix[RB][7], s_iyW[RB][7], s_HW[RB];
    __shared__ const float* s_fp[RB];

    int tid = threadIdx.x;                    // 0..127
    int gy = blockIdx.x;                      // local row-group (fast dim -> W L2 sharing)
    int p = p_base + blockIdx.y;              // panel index
    int row0 = (g0 + gy) * RB;
    int k0 = p * KC;

    if (tid < RB) {
        const int* pb = prep + (row0 + tid) * 20;
        int lvl = pb[0];
        s_fp[tid] = (lvl == 0 ? p2 : lvl == 1 ? p3 : lvl == 2 ? p4 : p5) + pb[1];
        s_HW[tid] = pb[2];
#pragma unroll
        for (int j = 0; j < 7; j++) { s_ix[tid][j] = pb[4 + j]; s_iyW[tid][j] = pb[12 + j]; }
    }
    __syncthreads();

    for (int e = tid; e < KT * RB; e += 128) {
        int kk = e >> 4;
        int r = e & 15;
        int k = k0 + kk;
        int c = k / 49;
        int pp = k - c * 49;
        int gyy = pp / 7;
        int gxx = pp - gyy * 7;
        xs[kk][r] = s_fp[r][c * s_HW[r] + s_iyW[r][gyy] + s_ix[r][gxx]];
    }
    __syncthreads();

    float acc[RB][8];
#pragma unroll
    for (int r = 0; r < RB; r++)
#pragma unroll
        for (int j = 0; j < 8; j++) acc[r][j] = 0.0f;

    const float* wp = W1 + (size_t)k0 * FCD + tid * 8;
    float wA[8], wB[8];
    LOAD8(wA, wp)
    for (int kk = 0; kk < KT; kk += 2) {
        LOAD8(wB, wp + (size_t)(kk + 1) * FCD)
        FMABLK(kk, wA)                        // k ascending: chain order preserved
        if (kk + 2 < KT) LOAD8(wA, wp + (size_t)(kk + 2) * FCD)
        FMABLK(kk + 1, wB)
    }

    size_t pstride = (size_t)gs * RB * FCD;
    float* po = part + (size_t)p * pstride + ((size_t)gy * RB) * FCD + tid * 8;
#pragma unroll
    for (int r = 0; r < RB; r++) {
#pragma unroll
        for (int j = 0; j < 8; j++) po[(size_t)r * FCD + j] = acc[r][j];
    }
}

// Ordered left-fold over the 33 panel chains + bias + ReLU. Exact OpenBLAS order:
// tot = ((chain0 + chain1) + chain2) + ...
__global__ void fc1_fold(const float* __restrict__ part, const float* __restrict__ b1,
                         float* __restrict__ X1, int row_base, int rows_s) {
    int idx = blockIdx.x * 256 + threadIdx.x;
    if (idx >= rows_s * FCD) return;
    size_t stride = (size_t)rows_s * FCD;
    float tot = part[idx];
    for (int p = 1; p < NPANEL; p++)
        tot = __fadd_rn(tot, part[(size_t)p * stride + idx]);
    int c = idx & (FCD - 1);
    float v = __fadd_rn(tot, b1[c]);
    X1[(size_t)row_base * FCD + idx] = fmaxf(v, 0.0f);
}

// ================= fallback / fc2 machinery (round-10, proven bit-exact) =================
#define FMA8(BUF, KB)                                                                   \
    _Pragma("unroll")                                                                   \
    for (int u = 0; u < 8; u++) {                                                       \
        const float4* xv = (const float4*)&xs[(KB) + u][0];                             \
        float4 a0 = xv[0], a1 = xv[1];                                                  \
        float wx = BUF[u].x, wy = BUF[u].y;                                             \
        acc[0][0] = fmaf(a0.x, wx, acc[0][0]); acc[0][1] = fmaf(a0.x, wy, acc[0][1]);   \
        acc[1][0] = fmaf(a0.y, wx, acc[1][0]); acc[1][1] = fmaf(a0.y, wy, acc[1][1]);   \
        acc[2][0] = fmaf(a0.z, wx, acc[2][0]); acc[2][1] = fmaf(a0.z, wy, acc[2][1]);   \
        acc[3][0] = fmaf(a0.w, wx, acc[3][0]); acc[3][1] = fmaf(a0.w, wy, acc[3][1]);   \
        acc[4][0] = fmaf(a1.x, wx, acc[4][0]); acc[4][1] = fmaf(a1.x, wy, acc[4][1]);   \
        acc[5][0] = fmaf(a1.y, wx, acc[5][0]); acc[5][1] = fmaf(a1.y, wy, acc[5][1]);   \
        acc[6][0] = fmaf(a1.z, wx, acc[6][0]); acc[6][1] = fmaf(a1.z, wy, acc[6][1]);   \
        acc[7][0] = fmaf(a1.w, wx, acc[7][0]); acc[7][1] = fmaf(a1.w, wy, acc[7][1]);   \
    }

template <int KT>
__device__ __forceinline__ void fc_panel2(const float* __restrict__ wp,
                                          const float (*xs)[R1],
                                          float acc[R1][2]) {
    float2 wa[8], wb[8];
#pragma unroll
    for (int u = 0; u < 8; u++) wa[u] = *(const float2*)(wp + (size_t)u * FCD);
    for (int kk = 0; kk < KT; kk += 16) {
#pragma unroll
        for (int u = 0; u < 8; u++)
            wb[u] = *(const float2*)(wp + (size_t)(kk + 8 + u) * FCD);
        FMA8(wa, kk)
        if (kk + 16 < KT) {
#pragma unroll
            for (int u = 0; u < 8; u++)
                wa[u] = *(const float2*)(wp + (size_t)(kk + 16 + u) * FCD);
        }
        FMA8(wb, kk + 8)
    }
}

__global__ __launch_bounds__(256) void fc1_fallback(
    const float* __restrict__ p2, const float* __restrict__ p3,
    const float* __restrict__ p4, const float* __restrict__ p5,
    const int* __restrict__ prep, const float* __restrict__ W1,
    const float* __restrict__ b1, float* __restrict__ X1) {
    __shared__ float xs[KC][R1];
    __shared__ int s_ix[R1][7], s_iyW[R1][7], s_HW[R1];
    __shared__ const float* s_fp[R1];

    int tid = threadIdx.x;
    int c0 = blockIdx.x * 512 + tid * 2;
    int row0 = blockIdx.y * R1;

    if (tid < R1) {
        const int* pb = prep + (row0 + tid) * 20;
        int lvl = pb[0];
        s_fp[tid] = (lvl == 0 ? p2 : lvl == 1 ? p3 : lvl == 2 ? p4 : p5) + pb[1];
        s_HW[tid] = pb[2];
#pragma unroll
        for (int j = 0; j < 7; j++) { s_ix[tid][j] = pb[4 + j]; s_iyW[tid][j] = pb[12 + j]; }
    }

    float tot[R1][2];
#pragma unroll
    for (int r = 0; r < R1; r++) { tot[r][0] = 0.0f; tot[r][1] = 0.0f; }

    for (int k0 = 0; k0 < FCIN; k0 += KC) {
        int kt = FCIN - k0; if (kt > KC) kt = KC;
        __syncthreads();
        for (int e = tid; e < kt * R1; e += 256) {
            int kk = e >> 3;
            int r = e & 7;
            int k = k0 + kk;
            int c = k / 49;
            int p = k - c * 49;
            int gy = p / 7;
            int gx = p - gy * 7;
            xs[kk][r] = s_fp[r][c * s_HW[r] + s_iyW[r][gy] + s_ix[r][gx]];
        }
        __syncthreads();

        float acc[R1][2];
#pragma unroll
        for (int r = 0; r < R1; r++) { acc[r][0] = 0.0f; acc[r][1] = 0.0f; }

        const float* wp = W1 + (size_t)k0 * FCD + c0;
        if (kt == KC) fc_panel2<KC>(wp, xs, acc);
        else          fc_panel2<256>(wp, xs, acc);

#pragma unroll
        for (int r = 0; r < R1; r++) {
            tot[r][0] = __fadd_rn(tot[r][0], acc[r][0]);
            tot[r][1] = __fadd_rn(tot[r][1], acc[r][1]);
        }
    }
    float bv0 = b1[c0], bv1 = b1[c0 + 1];
#pragma unroll
    for (int r = 0; r < R1; r++) {
        float v0 = __fadd_rn(tot[r][0], bv0);
        float v1 = __fadd_rn(tot[r][1], bv1);
        X1[(size_t)(row0 + r) * FCD + c0]     = fmaxf(v0, 0.0f);
        X1[(size_t)(row0 + r) * FCD + c0 + 1] = fmaxf(v1, 0.0f);
    }
}

__global__ __launch_bounds__(256) void fc2_seq(
    const float* __restrict__ X1, const float* __restrict__ W2,
    const float* __restrict__ b2, float* __restrict__ X2) {
    __shared__ float xs[KC][R1];
    int tid = threadIdx.x;
    int c0 = blockIdx.x * 512 + tid * 2;
    int row0 = blockIdx.y * R1;

    float tot[R1][2];
#pragma unroll
    for (int r = 0; r < R1; r++) { tot[r][0] = 0.0f; tot[r][1] = 0.0f; }

    for (int k0 = 0; k0 < FCD; k0 += KC) {
        int kt = FCD - k0; if (kt > KC) kt = KC;
        __syncthreads();
        for (int e = tid; e < kt * R1; e += 256) {
            int kk = e >> 3;
            int r = e & 7;
            xs[kk][r] = X1[(size_t)(row0 + r) * FCD + k0 + kk];
        }
        __syncthreads();

        float acc[R1][2];
#pragma unroll
        for (int r = 0; r < R1; r++) { acc[r][0] = 0.0f; acc[r][1] = 0.0f; }

        const float* wp = W2 + (size_t)k0 * FCD + c0;
        if (kt == KC) fc_panel2<KC>(wp, xs, acc);
        else          fc_panel2<256>(wp, xs, acc);

#pragma unroll
        for (int r = 0; r < R1; r++) {
            tot[r][0] = __fadd_rn(tot[r][0], acc[r][0]);
            tot[r][1] = __fadd_rn(tot[r][1], acc[r][1]);
        }
    }
    float bv0 = b2[c0], bv1 = b2[c0 + 1];
#pragma unroll
    for (int r = 0; r < R1; r++) {
        float v0 = __fadd_rn(tot[r][0], bv0);
        float v1 = __fadd_rn(tot[r][1], bv1);
        X2[(size_t)(row0 + r) * FCD + c0]     = fmaxf(v0, 0.0f);
        X2[(size_t)(row0 + r) * FCD + c0 + 1] = fmaxf(v1, 0.0f);
    }
}

// ---------------- Heads: 6 sgemm-order dots (KC panels), softmax, decode, clip ----------------
__global__ __launch_bounds__(256) void heads_seq(
    const float* __restrict__ X2,
    const float* __restrict__ Wc, const float* __restrict__ bc,
    const float* __restrict__ Wb, const float* __restrict__ bb_,
    const float* __restrict__ props, const int* __restrict__ img_sz,
    float* __restrict__ SC, float* __restrict__ BX) {
    int b = blockIdx.x;
    int tid = threadIdx.x;
    __shared__ float xsh[FCD];
    __shared__ float lg[6];
    for (int k = tid; k < FCD; k += 256) xsh[k] = X2[(size_t)b * FCD + k];
    __syncthreads();

    if (tid < 6) {
        const float* wp; int st; float bias;
        if (tid < 2) { wp = Wc + tid; st = 2; bias = bc[tid]; }
        else         { wp = Wb + (tid - 2); st = 4; bias = bb_[tid - 2]; }
        float tot = 0.0f;
        for (int k0 = 0; k0 < FCD; k0 += KC) {
            int kt = FCD - k0; if (kt > KC) kt = KC;
            float acc = 0.0f;
            for (int k = k0; k < k0 + kt; k++) acc = fmaf(xsh[k], wp[(size_t)k * st], acc);
            tot = __fadd_rn(tot, acc);
        }
        lg[tid] = __fadd_rn(tot, bias);
    }
    __syncthreads();

    if (tid == 0) {
        float c0 = lg[0], c1 = lg[1];
        float mx = fmaxf(c0, c1);
        float e0 = (float)exp((double)__fsub_rn(c0, mx));
        float e1 = (float)exp((double)__fsub_rn(c1, mx));
        SC[b] = __fdiv_rn(e1, __fadd_rn(e0, e1));

        int n = b / NBOX;
        const float* pr = props + (size_t)b * 4;
        float x1 = pr[0], y1 = pr[1], x2 = pr[2], y2 = pr[3];
        float w = __fsub_rn(x2, x1), h = __fsub_rn(y2, y1);
        float cx = __fadd_rn(x1, __fmul_rn(0.5f, w));
        float cy = __fadd_rn(y1, __fmul_rn(0.5f, h));
        float dx = lg[2], dy = lg[3];
        float dw = fminf(lg[4], SCALE_CLAMP_F);
        float dh = fminf(lg[5], SCALE_CLAMP_F);
        float pcx = __fadd_rn(__fmul_rn(dx, w), cx);
        float pcy = __fadd_rn(__fmul_rn(dy, h), cy);
        float pw = __fmul_rn((float)exp((double)dw), w);
        float ph = __fmul_rn((float)exp((double)dh), h);
        float bx1 = __fsub_rn(pcx, __fmul_rn(0.5f, pw));
        float by1 = __fsub_rn(pcy, __fmul_rn(0.5f, ph));
        float bx2 = __fadd_rn(pcx, __fmul_rn(0.5f, pw));
        float by2 = __fadd_rn(pcy, __fmul_rn(0.5f, ph));
        float Hf = (float)img_sz[n * 2 + 0], Wf = (float)img_sz[n * 2 + 1];
        bx1 = fminf(fmaxf(bx1, 0.0f), Wf);
        by1 = fminf(fmaxf(by1, 0.0f), Hf);
        bx2 = fminf(fmaxf(bx2, 0.0f), Wf);
        by2 = fminf(fmaxf(by2, 0.0f), Hf);
        BX[(size_t)b * 4 + 0] = bx1;
        BX[(size_t)b * 4 + 1] = by1;
        BX[(size_t)b * 4 + 2] = bx2;
        BX[(size_t)b * 4 + 3] = by2;
    }
}

// ---------------- Sort + NMS + topk (strict f32, numpy op order) ----------------
__global__ __launch_bounds__(1024) void nms_kernel(const float* __restrict__ SC,
                                                   const float* __restrict__ BX,
                                                   float* __restrict__ out) {
    int n = blockIdx.x;
    __shared__ float sraw[NBOX];
    __shared__ float ssort[NBOX];
    __shared__ float bsort[NBOX][4];
    __shared__ int ord[NBOX];
    __shared__ unsigned char keep[NBOX];
    int tid = threadIdx.x;

    for (int j = tid; j < NBOX; j += 1024) sraw[j] = SC[n * NBOX + j];
    __syncthreads();

    if (tid < NBOX) {
        float sj = sraw[tid];
        int r = 0;
        for (int k = 0; k < NBOX; k++) {
            float sk = sraw[k];
            r += (sk > sj) || (sk == sj && k < tid);
        }
        ord[r] = tid;
        ssort[r] = sj;
#pragma unroll
        for (int k = 0; k < 4; k++) bsort[r][k] = BX[((size_t)n * NBOX + tid) * 4 + k];
        keep[r] = (sj > 0.05f) ? 1 : 0;
    }
    __syncthreads();

    for (int i = 0; i < NBOX - 1; i++) {
        if (keep[i] && tid > i && tid < NBOX && keep[tid]) {
            float ax1 = bsort[i][0], ay1 = bsort[i][1], ax2 = bsort[i][2], ay2 = bsort[i][3];
            float bx1 = bsort[tid][0], by1 = bsort[tid][1], bx2 = bsort[tid][2], by2 = bsort[tid][3];
            float areaA = __fmul_rn(__fsub_rn(ax2, ax1), __fsub_rn(ay2, ay1));
            float areaB = __fmul_rn(__fsub_rn(bx2, bx1), __fsub_rn(by2, by1));
            float ix1 = fmaxf(ax1, bx1), iy1 = fmaxf(ay1, by1);
            float ix2 = fminf(ax2, bx2), iy2 = fminf(ay2, by2);
            float iw = fmaxf(__fsub_rn(ix2, ix1), 0.0f);
            float ih = fmaxf(__fsub_rn(iy2, iy1), 0.0f);
            float inter = __fmul_rn(iw, ih);
            float denom = fmaxf(__fsub_rn(__fadd_rn(areaA, areaB), inter), 1e-9f);
            if (__fdiv_rn(inter, denom) > 0.5f) keep[tid] = 0;
        }
        __syncthreads();
    }

    if (tid == 0) {
        int c = 0;
        for (int r = 0; r < NBOX; r++) {
            int k = keep[r];
            c += k;
            keep[r] = (k && (c <= TOPK)) ? 1 : 0;
        }
    }
    __syncthreads();

    float* boxes_o = out;
    float* scores_o = out + (size_t)NIMG * NBOX * 4;
    float* keep_o = scores_o + (size_t)NIMG * NBOX;
    float* ord_o = keep_o + (size_t)NIMG * NBOX;
    for (int r = tid; r < NBOX; r += 1024) {
#pragma unroll
        for (int k = 0; k < 4; k++)
            boxes_o[((size_t)n * NBOX + r) * 4 + k] = bsort[r][k];
        scores_o[n * NBOX + r] = ssort[r];
        keep_o[n * NBOX + r] = (float)keep[r];
        ord_o[n * NBOX + r] = (float)ord[r];
    }
}

extern "C" void kernel_launch(void* const* d_in, const int* in_sizes, int n_in,
                              void* d_out, int out_size, void* d_ws, size_t ws_size,
                              hipStream_t stream) {
    const float* p2 = (const float*)d_in[0];
    const float* p3 = (const float*)d_in[1];
    const float* p4 = (const float*)d_in[2];
    const float* p5 = (const float*)d_in[3];
    const float* props = (const float*)d_in[4];
    const int* img = (const int*)d_in[5];
    const float* W1 = (const float*)d_in[6];
    const float* b1 = (const float*)d_in[7];
    const float* W2 = (const float*)d_in[8];
    const float* b2 = (const float*)d_in[9];
    const float* Wc = (const float*)d_in[10];
    const float* bc = (const float*)d_in[11];
    const float* Wb = (const float*)d_in[12];
    const float* bb = (const float*)d_in[13];

    float* X1 = (float*)d_ws;
    float* X2 = X1 + (size_t)2000 * FCD;
    float* SCf = X2 + (size_t)2000 * FCD;
    float* BXf = SCf + 2000;
    int* prep = (int*)(BXf + 8000);
    float* part = (float*)(prep + 2000 * 20);
    size_t used = (size_t)((char*)part - (char*)d_ws);
    size_t avail = ws_size > used ? ws_size - used : 0;

    prep_kernel<<<(NIMG * NBOX + 255) / 256, 256, 0, stream>>>(props, prep);

    // pick largest sweep size whose partial buffer fits d_ws
    int gmax = 0;
    const int cand[4] = {125, 63, 32, 16};
    for (int i = 0; i < 4; i++) {
        size_t need = (size_t)NPANEL * cand[i] * RB * FCD * sizeof(float);
        if (need <= avail) { gmax = cand[i]; break; }
    }

    if (gmax > 0) {
        for (int g0 = 0; g0 < NGROUP; g0 += gmax) {
            int gs = NGROUP - g0; if (gs > gmax) gs = gmax;
            dim3 gA(gs, NPANEL - 1);   // panels 0..31 (KT=384)
            fc1_panel<KC><<<gA, 128, 0, stream>>>(p2, p3, p4, p5, prep, W1, part, g0, gs, 0);
            dim3 gB(gs, 1);            // panel 32 (KT=256)
            fc1_panel<256><<<gB, 128, 0, stream>>>(p2, p3, p4, p5, prep, W1, part, g0, gs, 32);
            int rows_s = gs * RB;
            int nelem = rows_s * FCD;
            fc1_fold<<<(nelem + 255) / 256, 256, 0, stream>>>(part, b1, X1, g0 * RB, rows_s);
        }
    } else {
        dim3 gfc(2, (NIMG * NBOX) / R1);   // (2, 250) -- proven round-10 path
        fc1_fallback<<<gfc, 256, 0, stream>>>(p2, p3, p4, p5, prep, W1, b1, X1);
    }

    dim3 gfc2(2, (NIMG * NBOX) / R1);      // (2, 250)
    fc2_seq<<<gfc2, 256, 0, stream>>>(X1, W2, b2, X2);

    heads_seq<<<NIMG * NBOX, 256, 0, stream>>>(X2, Wc, bc, Wb, bb, props, img, SCf, BXf);

    nms_kernel<<<NIMG, 1024, 0, stream>>>(SCf, BXf, (float*)d_out);
}

// Round 13
// 1177.042 us; speedup vs baseline: 1.3044x; 1.1265x over previous
//
#include <hip/hip_runtime.h>
#include <math.h>

#define NBOX 1000
#define NIMG 2
#define CCH 256
#define FCIN 12544   // 256*7*7
#define FCD 1024
#define TOPK 100
#define SCALE_CLAMP_F ((float)4.135166556742356)  // f32(np.log(1000/16))
#define KC 384       // OpenBLAS SGEMM_DEFAULT_Q -- FROZEN numerics invariant
#define NPANEL 33    // 12544 = 32*384 + 256
#define RB 16        // rows per panel-block
#define NGROUP 125   // 2000/16
#define CHUNK 128    // LDS staging chunk (divides 384 and 256)
#define R1 8         // rows per block, fallback/fc2 path

// ---------------- Prep: per-box level + gather indices (strict f32, numpy op order) ----------------
__global__ void prep_kernel(const float* __restrict__ props, int* __restrict__ prep) {
    int b = blockIdx.x * blockDim.x + threadIdx.x;
    if (b >= NIMG * NBOX) return;
    int n = b / NBOX;
    const float* pr = props + (size_t)b * 4;
    float x1 = pr[0], y1 = pr[1], x2 = pr[2], y2 = pr[3];

    float w = __fsub_rn(x2, x1), h = __fsub_rn(y2, y1);
    float s = sqrtf(fmaxf(__fmul_rn(w, h), 1e-6f));
    float l2 = (float)log2((double)__fadd_rn(__fdiv_rn(s, 224.0f), 1e-8f));
    float lv = floorf(__fadd_rn(4.0f, l2));
    lv = fminf(fmaxf(lv, 2.0f), 5.0f);
    int lvl = (int)lv - 2;

    int H, W; float scale;
    if (lvl == 0)      { H = 200; W = 304; scale = 0.25f; }
    else if (lvl == 1) { H = 100; W = 152; scale = 0.125f; }
    else if (lvl == 2) { H = 50;  W = 76;  scale = 0.0625f; }
    else               { H = 25;  W = 38;  scale = 0.03125f; }

    float xs1 = __fmul_rn(x1, scale), ys1 = __fmul_rn(y1, scale);
    float xs2 = __fmul_rn(x2, scale), ys2 = __fmul_rn(y2, scale);
    float bw = __fdiv_rn(fmaxf(__fsub_rn(xs2, xs1), 1.0f), 7.0f);
    float bh = __fdiv_rn(fmaxf(__fsub_rn(ys2, ys1), 1.0f), 7.0f);

    int* pb = prep + b * 20;
    pb[0] = lvl;
    pb[1] = n * CCH * H * W;
    pb[2] = H * W;
#pragma unroll
    for (int i = 0; i < 7; i++) {
        float cs = (float)i + 0.5f;
        float gx = __fadd_rn(xs1, __fmul_rn(cs, bw));
        float gy = __fadd_rn(ys1, __fmul_rn(cs, bh));
        int vx = (int)gx;
        int vy = (int)gy;
        vx = vx < 0 ? 0 : (vx > W - 1 ? W - 1 : vx);
        vy = vy < 0 ? 0 : (vy > H - 1 ? H - 1 : vy);
        pb[4 + i] = vx;
        pb[12 + i] = vy * W;
    }
}

// ================= Panel-parallel FC1 =================
// One block = one panel p x 16 rows x all 1024 cols (256 thr x 4 cols).
// LDS staged in 128-k chunks; accumulator carries across chunks -> exact ascending-k chain.
#define FMASTEP(KB, WV)                                               \
    {                                                                 \
        const float4* xv = (const float4*)&xs[(KB)][0];               \
        float4 a0 = xv[0], a1 = xv[1], a2 = xv[2], a3 = xv[3];        \
        float xr[16] = {a0.x, a0.y, a0.z, a0.w, a1.x, a1.y, a1.z, a1.w, \
                        a2.x, a2.y, a2.z, a2.w, a3.x, a3.y, a3.z, a3.w}; \
        _Pragma("unroll")                                             \
        for (int r = 0; r < RB; r++) {                                \
            acc[r][0] = fmaf(xr[r], WV.x, acc[r][0]);                 \
            acc[r][1] = fmaf(xr[r], WV.y, acc[r][1]);                 \
            acc[r][2] = fmaf(xr[r], WV.z, acc[r][2]);                 \
            acc[r][3] = fmaf(xr[r], WV.w, acc[r][3]);                 \
        }                                                             \
    }

__global__ __launch_bounds__(256, 4) void fc1_panel(
    const float* __restrict__ p2, const float* __restrict__ p3,
    const float* __restrict__ p4, const float* __restrict__ p5,
    const int* __restrict__ prep, const float* __restrict__ W1,
    float* __restrict__ part, int g0, int gs) {
    __shared__ float xs[CHUNK][RB];
    __shared__ int s_ix[RB][7], s_iyW[RB][7], s_HW[RB];
    __shared__ const float* s_fp[RB];

    int tid = threadIdx.x;                    // 0..255
    int gy = blockIdx.x;                      // local row-group (fast dim -> W L2 sharing per panel)
    int p = blockIdx.y;                       // panel index 0..32
    int row0 = (g0 + gy) * RB;
    int k0 = p * KC;
    int kt = (p == NPANEL - 1) ? 256 : KC;    // 256 or 384, both %128==0

    if (tid < RB) {
        const int* pb = prep + (row0 + tid) * 20;
        int lvl = pb[0];
        s_fp[tid] = (lvl == 0 ? p2 : lvl == 1 ? p3 : lvl == 2 ? p4 : p5) + pb[1];
        s_HW[tid] = pb[2];
#pragma unroll
        for (int j = 0; j < 7; j++) { s_ix[tid][j] = pb[4 + j]; s_iyW[tid][j] = pb[12 + j]; }
    }
    __syncthreads();

    float acc[RB][4];
#pragma unroll
    for (int r = 0; r < RB; r++)
#pragma unroll
        for (int j = 0; j < 4; j++) acc[r][j] = 0.0f;

    const float* wp = W1 + (size_t)k0 * FCD + tid * 4;

    for (int ck = 0; ck < kt; ck += CHUNK) {
        // stage this chunk's x fragment (gather)
        for (int e = tid; e < CHUNK * RB; e += 256) {
            int kk = e >> 4;
            int r = e & 15;
            int k = k0 + ck + kk;
            int c = k / 49;
            int pp = k - c * 49;
            int gyy = pp / 7;
            int gxx = pp - gyy * 7;
            xs[kk][r] = s_fp[r][c * s_HW[r] + s_iyW[r][gyy] + s_ix[r][gxx]];
        }
        __syncthreads();

        const float* wc = wp + (size_t)ck * FCD;
        float4 wA = *(const float4*)wc;
        for (int kk = 0; kk < CHUNK; kk += 2) {
            float4 wB = *(const float4*)(wc + (size_t)(kk + 1) * FCD);
            FMASTEP(kk, wA)                   // k ascending: chain order preserved
            if (kk + 2 < CHUNK) wA = *(const float4*)(wc + (size_t)(kk + 2) * FCD);
            FMASTEP(kk + 1, wB)
        }
        __syncthreads();
    }

    size_t pstride = (size_t)gs * RB * FCD;
    float* po = part + (size_t)p * pstride + ((size_t)gy * RB) * FCD + tid * 4;
#pragma unroll
    for (int r = 0; r < RB; r++) {
        float4 v = make_float4(acc[r][0], acc[r][1], acc[r][2], acc[r][3]);
        *(float4*)(po + (size_t)r * FCD) = v;
    }
}

// Ordered left-fold over the 33 panel chains + bias + ReLU. Exact OpenBLAS order.
__global__ void fc1_fold(const float* __restrict__ part, const float* __restrict__ b1,
                         float* __restrict__ X1, int row_base, int rows_s) {
    int idx = blockIdx.x * 256 + threadIdx.x;
    if (idx >= rows_s * FCD) return;
    size_t stride = (size_t)rows_s * FCD;
    float tot = part[idx];
    for (int p = 1; p < NPANEL; p++)
        tot = __fadd_rn(tot, part[(size_t)p * stride + idx]);
    int c = idx & (FCD - 1);
    float v = __fadd_rn(tot, b1[c]);
    X1[(size_t)row_base * FCD + idx] = fmaxf(v, 0.0f);
}

// ================= fallback / fc2 machinery (round-10, proven bit-exact) =================
#define FMA8(BUF, KB)                                                                   \
    _Pragma("unroll")                                                                   \
    for (int u = 0; u < 8; u++) {                                                       \
        const float4* xv = (const float4*)&xs[(KB) + u][0];                             \
        float4 a0 = xv[0], a1 = xv[1];                                                  \
        float wx = BUF[u].x, wy = BUF[u].y;                                             \
        acc[0][0] = fmaf(a0.x, wx, acc[0][0]); acc[0][1] = fmaf(a0.x, wy, acc[0][1]);   \
        acc[1][0] = fmaf(a0.y, wx, acc[1][0]); acc[1][1] = fmaf(a0.y, wy, acc[1][1]);   \
        acc[2][0] = fmaf(a0.z, wx, acc[2][0]); acc[2][1] = fmaf(a0.z, wy, acc[2][1]);   \
        acc[3][0] = fmaf(a0.w, wx, acc[3][0]); acc[3][1] = fmaf(a0.w, wy, acc[3][1]);   \
        acc[4][0] = fmaf(a1.x, wx, acc[4][0]); acc[4][1] = fmaf(a1.x, wy, acc[4][1]);   \
        acc[5][0] = fmaf(a1.y, wx, acc[5][0]); acc[5][1] = fmaf(a1.y, wy, acc[5][1]);   \
        acc[6][0] = fmaf(a1.z, wx, acc[6][0]); acc[6][1] = fmaf(a1.z, wy, acc[6][1]);   \
        acc[7][0] = fmaf(a1.w, wx, acc[7][0]); acc[7][1] = fmaf(a1.w, wy, acc[7][1]);   \
    }

template <int KT>
__device__ __forceinline__ void fc_panel2(const float* __restrict__ wp,
                                          const float (*xs)[R1],
                                          float acc[R1][2]) {
    float2 wa[8], wb[8];
#pragma unroll
    for (int u = 0; u < 8; u++) wa[u] = *(const float2*)(wp + (size_t)u * FCD);
    for (int kk = 0; kk < KT; kk += 16) {
#pragma unroll
        for (int u = 0; u < 8; u++)
            wb[u] = *(const float2*)(wp + (size_t)(kk + 8 + u) * FCD);
        FMA8(wa, kk)
        if (kk + 16 < KT) {
#pragma unroll
            for (int u = 0; u < 8; u++)
                wa[u] = *(const float2*)(wp + (size_t)(kk + 16 + u) * FCD);
        }
        FMA8(wb, kk + 8)
    }
}

__global__ __launch_bounds__(256) void fc1_fallback(
    const float* __restrict__ p2, const float* __restrict__ p3,
    const float* __restrict__ p4, const float* __restrict__ p5,
    const int* __restrict__ prep, const float* __restrict__ W1,
    const float* __restrict__ b1, float* __restrict__ X1) {
    __shared__ float xs[KC][R1];
    __shared__ int s_ix[R1][7], s_iyW[R1][7], s_HW[R1];
    __shared__ const float* s_fp[R1];

    int tid = threadIdx.x;
    int c0 = blockIdx.x * 512 + tid * 2;
    int row0 = blockIdx.y * R1;

    if (tid < R1) {
        const int* pb = prep + (row0 + tid) * 20;
        int lvl = pb[0];
        s_fp[tid] = (lvl == 0 ? p2 : lvl == 1 ? p3 : lvl == 2 ? p4 : p5) + pb[1];
        s_HW[tid] = pb[2];
#pragma unroll
        for (int j = 0; j < 7; j++) { s_ix[tid][j] = pb[4 + j]; s_iyW[tid][j] = pb[12 + j]; }
    }

    float tot[R1][2];
#pragma unroll
    for (int r = 0; r < R1; r++) { tot[r][0] = 0.0f; tot[r][1] = 0.0f; }

    for (int k0 = 0; k0 < FCIN; k0 += KC) {
        int kt = FCIN - k0; if (kt > KC) kt = KC;
        __syncthreads();
        for (int e = tid; e < kt * R1; e += 256) {
            int kk = e >> 3;
            int r = e & 7;
            int k = k0 + kk;
            int c = k / 49;
            int p = k - c * 49;
            int gy = p / 7;
            int gx = p - gy * 7;
            xs[kk][r] = s_fp[r][c * s_HW[r] + s_iyW[r][gy] + s_ix[r][gx]];
        }
        __syncthreads();

        float acc[R1][2];
#pragma unroll
        for (int r = 0; r < R1; r++) { acc[r][0] = 0.0f; acc[r][1] = 0.0f; }

        const float* wp = W1 + (size_t)k0 * FCD + c0;
        if (kt == KC) fc_panel2<KC>(wp, xs, acc);
        else          fc_panel2<256>(wp, xs, acc);

#pragma unroll
        for (int r = 0; r < R1; r++) {
            tot[r][0] = __fadd_rn(tot[r][0], acc[r][0]);
            tot[r][1] = __fadd_rn(tot[r][1], acc[r][1]);
        }
    }
    float bv0 = b1[c0], bv1 = b1[c0 + 1];
#pragma unroll
    for (int r = 0; r < R1; r++) {
        float v0 = __fadd_rn(tot[r][0], bv0);
        float v1 = __fadd_rn(tot[r][1], bv1);
        X1[(size_t)(row0 + r) * FCD + c0]     = fmaxf(v0, 0.0f);
        X1[(size_t)(row0 + r) * FCD + c0 + 1] = fmaxf(v1, 0.0f);
    }
}

__global__ __launch_bounds__(256) void fc2_seq(
    const float* __restrict__ X1, const float* __restrict__ W2,
    const float* __restrict__ b2, float* __restrict__ X2) {
    __shared__ float xs[KC][R1];
    int tid = threadIdx.x;
    int c0 = blockIdx.x * 512 + tid * 2;
    int row0 = blockIdx.y * R1;

    float tot[R1][2];
#pragma unroll
    for (int r = 0; r < R1; r++) { tot[r][0] = 0.0f; tot[r][1] = 0.0f; }

    for (int k0 = 0; k0 < FCD; k0 += KC) {
        int kt = FCD - k0; if (kt > KC) kt = KC;
        __syncthreads();
        for (int e = tid; e < kt * R1; e += 256) {
            int kk = e >> 3;
            int r = e & 7;
            xs[kk][r] = X1[(size_t)(row0 + r) * FCD + k0 + kk];
        }
        __syncthreads();

        float acc[R1][2];
#pragma unroll
        for (int r = 0; r < R1; r++) { acc[r][0] = 0.0f; acc[r][1] = 0.0f; }

        const float* wp = W2 + (size_t)k0 * FCD + c0;
        if (kt == KC) fc_panel2<KC>(wp, xs, acc);
        else          fc_panel2<256>(wp, xs, acc);

#pragma unroll
        for (int r = 0; r < R1; r++) {
            tot[r][0] = __fadd_rn(tot[r][0], acc[r][0]);
            tot[r][1] = __fadd_rn(tot[r][1], acc[r][1]);
        }
    }
    float bv0 = b2[c0], bv1 = b2[c0 + 1];
#pragma unroll
    for (int r = 0; r < R1; r++) {
        float v0 = __fadd_rn(tot[r][0], bv0);
        float v1 = __fadd_rn(tot[r][1], bv1);
        X2[(size_t)(row0 + r) * FCD + c0]     = fmaxf(v0, 0.0f);
        X2[(size_t)(row0 + r) * FCD + c0 + 1] = fmaxf(v1, 0.0f);
    }
}

// ---------------- Heads: 6 sgemm-order dots (KC panels), softmax, decode, clip ----------------
__global__ __launch_bounds__(256) void heads_seq(
    const float* __restrict__ X2,
    const float* __restrict__ Wc, const float* __restrict__ bc,
    const float* __restrict__ Wb, const float* __restrict__ bb_,
    const float* __restrict__ props, const int* __restrict__ img_sz,
    float* __restrict__ SC, float* __restrict__ BX) {
    int b = blockIdx.x;
    int tid = threadIdx.x;
    __shared__ float xsh[FCD];
    __shared__ float lg[6];
    for (int k = tid; k < FCD; k += 256) xsh[k] = X2[(size_t)b * FCD + k];
    __syncthreads();

    if (tid < 6) {
        const float* wp; int st; float bias;
        if (tid < 2) { wp = Wc + tid; st = 2; bias = bc[tid]; }
        else         { wp = Wb + (tid - 2); st = 4; bias = bb_[tid - 2]; }
        float tot = 0.0f;
        for (int k0 = 0; k0 < FCD; k0 += KC) {
            int kt = FCD - k0; if (kt > KC) kt = KC;
            float acc = 0.0f;
            for (int k = k0; k < k0 + kt; k++) acc = fmaf(xsh[k], wp[(size_t)k * st], acc);
            tot = __fadd_rn(tot, acc);
        }
        lg[tid] = __fadd_rn(tot, bias);
    }
    __syncthreads();

    if (tid == 0) {
        float c0 = lg[0], c1 = lg[1];
        float mx = fmaxf(c0, c1);
        float e0 = (float)exp((double)__fsub_rn(c0, mx));
        float e1 = (float)exp((double)__fsub_rn(c1, mx));
        SC[b] = __fdiv_rn(e1, __fadd_rn(e0, e1));

        int n = b / NBOX;
        const float* pr = props + (size_t)b * 4;
        float x1 = pr[0], y1 = pr[1], x2 = pr[2], y2 = pr[3];
        float w = __fsub_rn(x2, x1), h = __fsub_rn(y2, y1);
        float cx = __fadd_rn(x1, __fmul_rn(0.5f, w));
        float cy = __fadd_rn(y1, __fmul_rn(0.5f, h));
        float dx = lg[2], dy = lg[3];
        float dw = fminf(lg[4], SCALE_CLAMP_F);
        float dh = fminf(lg[5], SCALE_CLAMP_F);
        float pcx = __fadd_rn(__fmul_rn(dx, w), cx);
        float pcy = __fadd_rn(__fmul_rn(dy, h), cy);
        float pw = __fmul_rn((float)exp((double)dw), w);
        float ph = __fmul_rn((float)exp((double)dh), h);
        float bx1 = __fsub_rn(pcx, __fmul_rn(0.5f, pw));
        float by1 = __fsub_rn(pcy, __fmul_rn(0.5f, ph));
        float bx2 = __fadd_rn(pcx, __fmul_rn(0.5f, pw));
        float by2 = __fadd_rn(pcy, __fmul_rn(0.5f, ph));
        float Hf = (float)img_sz[n * 2 + 0], Wf = (float)img_sz[n * 2 + 1];
        bx1 = fminf(fmaxf(bx1, 0.0f), Wf);
        by1 = fminf(fmaxf(by1, 0.0f), Hf);
        bx2 = fminf(fmaxf(bx2, 0.0f), Wf);
        by2 = fminf(fmaxf(by2, 0.0f), Hf);
        BX[(size_t)b * 4 + 0] = bx1;
        BX[(size_t)b * 4 + 1] = by1;
        BX[(size_t)b * 4 + 2] = bx2;
        BX[(size_t)b * 4 + 3] = by2;
    }
}

// ---------------- Sort + NMS + topk (strict f32, numpy op order) ----------------
__global__ __launch_bounds__(1024) void nms_kernel(const float* __restrict__ SC,
                                                   const float* __restrict__ BX,
                                                   float* __restrict__ out) {
    int n = blockIdx.x;
    __shared__ float sraw[NBOX];
    __shared__ float ssort[NBOX];
    __shared__ float bsort[NBOX][4];
    __shared__ int ord[NBOX];
    __shared__ unsigned char keep[NBOX];
    int tid = threadIdx.x;

    for (int j = tid; j < NBOX; j += 1024) sraw[j] = SC[n * NBOX + j];
    __syncthreads();

    if (tid < NBOX) {
        float sj = sraw[tid];
        int r = 0;
        for (int k = 0; k < NBOX; k++) {
            float sk = sraw[k];
            r += (sk > sj) || (sk == sj && k < tid);
        }
        ord[r] = tid;
        ssort[r] = sj;
#pragma unroll
        for (int k = 0; k < 4; k++) bsort[r][k] = BX[((size_t)n * NBOX + tid) * 4 + k];
        keep[r] = (sj > 0.05f) ? 1 : 0;
    }
    __syncthreads();

    for (int i = 0; i < NBOX - 1; i++) {
        if (keep[i] && tid > i && tid < NBOX && keep[tid]) {
            float ax1 = bsort[i][0], ay1 = bsort[i][1], ax2 = bsort[i][2], ay2 = bsort[i][3];
            float bx1 = bsort[tid][0], by1 = bsort[tid][1], bx2 = bsort[tid][2], by2 = bsort[tid][3];
            float areaA = __fmul_rn(__fsub_rn(ax2, ax1), __fsub_rn(ay2, ay1));
            float areaB = __fmul_rn(__fsub_rn(bx2, bx1), __fsub_rn(by2, by1));
            float ix1 = fmaxf(ax1, bx1), iy1 = fmaxf(ay1, by1);
            float ix2 = fminf(ax2, bx2), iy2 = fminf(ay2, by2);
            float iw = fmaxf(__fsub_rn(ix2, ix1), 0.0f);
            float ih = fmaxf(__fsub_rn(iy2, iy1), 0.0f);
            float inter = __fmul_rn(iw, ih);
            float denom = fmaxf(__fsub_rn(__fadd_rn(areaA, areaB), inter), 1e-9f);
            if (__fdiv_rn(inter, denom) > 0.5f) keep[tid] = 0;
        }
        __syncthreads();
    }

    if (tid == 0) {
        int c = 0;
        for (int r = 0; r < NBOX; r++) {
            int k = keep[r];
            c += k;
            keep[r] = (k && (c <= TOPK)) ? 1 : 0;
        }
    }
    __syncthreads();

    float* boxes_o = out;
    float* scores_o = out + (size_t)NIMG * NBOX * 4;
    float* keep_o = scores_o + (size_t)NIMG * NBOX;
    float* ord_o = keep_o + (size_t)NIMG * NBOX;
    for (int r = tid; r < NBOX; r += 1024) {
#pragma unroll
        for (int k = 0; k < 4; k++)
            boxes_o[((size_t)n * NBOX + r) * 4 + k] = bsort[r][k];
        scores_o[n * NBOX + r] = ssort[r];
        keep_o[n * NBOX + r] = (float)keep[r];
        ord_o[n * NBOX + r] = (float)ord[r];
    }
}

extern "C" void kernel_launch(void* const* d_in, const int* in_sizes, int n_in,
                              void* d_out, int out_size, void* d_ws, size_t ws_size,
                              hipStream_t stream) {
    const float* p2 = (const float*)d_in[0];
    const float* p3 = (const float*)d_in[1];
    const float* p4 = (const float*)d_in[2];
    const float* p5 = (const float*)d_in[3];
    const float* props = (const float*)d_in[4];
    const int* img = (const int*)d_in[5];
    const float* W1 = (const float*)d_in[6];
    const float* b1 = (const float*)d_in[7];
    const float* W2 = (const float*)d_in[8];
    const float* b2 = (const float*)d_in[9];
    const float* Wc = (const float*)d_in[10];
    const float* bc = (const float*)d_in[11];
    const float* Wb = (const float*)d_in[12];
    const float* bb = (const float*)d_in[13];

    float* X1 = (float*)d_ws;
    float* X2 = X1 + (size_t)2000 * FCD;
    float* SCf = X2 + (size_t)2000 * FCD;
    float* BXf = SCf + 2000;
    int* prep = (int*)(BXf + 8000);
    float* part = (float*)(prep + 2000 * 20);
    size_t used = (size_t)((char*)part - (char*)d_ws);
    size_t avail = ws_size > used ? ws_size - used : 0;

    prep_kernel<<<(NIMG * NBOX + 255) / 256, 256, 0, stream>>>(props, prep);

    // pick largest sweep size whose partial buffer fits d_ws
    int gmax = 0;
    const int cand[4] = {125, 63, 32, 16};
    for (int i = 0; i < 4; i++) {
        size_t need = (size_t)NPANEL * cand[i] * RB * FCD * sizeof(float);
        if (need <= avail) { gmax = cand[i]; break; }
    }

    if (gmax > 0) {
        for (int g0 = 0; g0 < NGROUP; g0 += gmax) {
            int gs = NGROUP - g0; if (gs > gmax) gs = gmax;
            dim3 gA(gs, NPANEL);       // all 33 panels, runtime kt inside
            fc1_panel<<<gA, 256, 0, stream>>>(p2, p3, p4, p5, prep, W1, part, g0, gs);
            int rows_s = gs * RB;
            int nelem = rows_s * FCD;
            fc1_fold<<<(nelem + 255) / 256, 256, 0, stream>>>(part, b1, X1, g0 * RB, rows_s);
        }
    } else {
        dim3 gfc(2, (NIMG * NBOX) / R1);   // (2, 250) -- proven round-10 path
        fc1_fallback<<<gfc, 256, 0, stream>>>(p2, p3, p4, p5, prep, W1, b1, X1);
    }

    dim3 gfc2(2, (NIMG * NBOX) / R1);      // (2, 250)
    fc2_seq<<<gfc2, 256, 0, stream>>>(X1, W2, b2, X2);

    heads_seq<<<NIMG * NBOX, 256, 0, stream>>>(X2, Wc, bc, Wb, bb, props, img, SCf, BXf);

    nms_kernel<<<NIMG, 1024, 0, stream>>>(SCf, BXf, (float*)d_out);
}